// Round 2
// baseline (157.661 us; speedup 1.0000x reference)
//
#include <hip/hip_runtime.h>
#include <hip/hip_bf16.h>

// Problem constants (fixed by reference): B=4, C=64, H=W=64, N=4096
#define BATCH 4
#define CCH   64
#define NSP   4096

typedef __bf16 bf16x8v __attribute__((ext_vector_type(8)));
typedef __bf16 bf16x4v __attribute__((ext_vector_type(4)));
typedef float  floatx4 __attribute__((ext_vector_type(4)));

// ---------------------------------------------------------------------------
// Kernel 1: qkT[b][n][o] = bf16( sum_c W[o][c]*x[b][c][n] + bias[o] )
// Layout [B][N][C] so kernel 2 can stage K tiles with straight 16B copies and
// load Q A-frags as contiguous 16B.
// ---------------------------------------------------------------------------
__global__ __launch_bounds__(256) void qk_kernel(const float* __restrict__ x,
                                                 const float* __restrict__ Wm,
                                                 const float* __restrict__ bias,
                                                 __bf16* __restrict__ qkT) {
    __shared__ float Wt[64 * 65];   // W transposed: Wt[c][o], pad 65 vs bank conflicts
    __shared__ float xs[64 * 65];   // x tile: xs[c][j], j = n - n0

    const int t  = threadIdx.x;
    const int b  = blockIdx.x >> 6;
    const int n0 = (blockIdx.x & 63) << 6;

#pragma unroll
    for (int i = 0; i < 16; ++i) {
        int idx = t + 256 * i;            // 4096 elements each
        int r = idx >> 6, j = idx & 63;
        Wt[j * 65 + r] = Wm[idx];                          // Wt[c][o] = W[o][c]
        xs[r * 65 + j] = x[(b * 64 + r) * 4096 + n0 + j];  // xs[c][j] = x[b][c][n0+j]
    }
    __syncthreads();

    const int o = t & 63;
    const float bo = bias[o];
    for (int nn = (t >> 6); nn < 64; nn += 4) {
        float acc = bo;
#pragma unroll
        for (int c = 0; c < 64; ++c)
            acc = fmaf(Wt[c * 65 + o], xs[c * 65 + nn], acc);
        qkT[(b * 4096 + n0 + nn) * 64 + o] = (__bf16)acc;  // contiguous in o
    }
}

// ---------------------------------------------------------------------------
// Kernel 2: flash-style attention. One block per (b, 64-query tile).
// 4 waves; wave w owns queries n0 + w*16 .. +15.
// Scores are tiny (|s| <= ~0.4) -> softmax without max subtraction is safe.
// ---------------------------------------------------------------------------
#define KSTRIDE 72   // bf16 elements per LDS row (64 + 8 pad -> 16B-aligned rows, 2-way banks)
#define OSTRIDE 68   // fp32 elements per epilogue LDS row (16B-aligned rows)

__global__ __launch_bounds__(256) void attn_kernel(const float* __restrict__ x,
                                                   const __bf16* __restrict__ qkT,
                                                   float* __restrict__ out) {
    __shared__ __align__(16) char smem[27648];
    __bf16* Klds = (__bf16*)smem;                 // [64 m][KSTRIDE c]
    __bf16* Vlds = (__bf16*)(smem + 9216);        // [64 c][KSTRIDE m]
    __bf16* Plds = (__bf16*)(smem + 18432);       // [4 waves][16 q][KSTRIDE m]
    float*  Olds = (float*)smem;                  // epilogue: [64 c][OSTRIDE n] (aliases K/V/P)

    const int t    = threadIdx.x;
    const int b    = blockIdx.x >> 6;
    const int n0   = (blockIdx.x & 63) << 6;
    const int w    = t >> 6;
    const int lane = t & 63;
    const int quad = lane >> 4;
    const int l16  = lane & 15;

    // Q A-frags for this wave's 16 queries: A[m=l16][k=quad*8+j], k = channel c
    const __bf16* qrow = qkT + (size_t)(b * 4096 + n0 + w * 16 + l16) * 64;
    const bf16x8v fq0 = *(const bf16x8v*)(qrow + quad * 8);
    const bf16x8v fq1 = *(const bf16x8v*)(qrow + 32 + quad * 8);

    floatx4 o0 = {0.f, 0.f, 0.f, 0.f};
    floatx4 o1 = {0.f, 0.f, 0.f, 0.f};
    floatx4 o2 = {0.f, 0.f, 0.f, 0.f};
    floatx4 o3 = {0.f, 0.f, 0.f, 0.f};
    float rs[4] = {0.f, 0.f, 0.f, 0.f};
    const float scale = 1.0f / 4096.0f;

    for (int m0 = 0; m0 < 4096; m0 += 64) {
        __syncthreads();   // previous iteration's K/V frag reads complete
        // ---- stage K tile: Klds[m][c] = qkT[b][m0+m][c] (straight copy, 16B chunks)
#pragma unroll
        for (int i = 0; i < 2; ++i) {
            int idx = t + 256 * i;                  // 512 chunks of 16B
            int row = idx >> 3, c8 = idx & 7;
            *(uint4*)(Klds + row * KSTRIDE + c8 * 8) =
                *(const uint4*)(qkT + (size_t)(b * 4096 + m0 + row) * 64 + c8 * 8);
        }
        // ---- stage V tile (c-major): Vlds[c][m] = bf16(x[b][c][m0+m])
#pragma unroll
        for (int i = 0; i < 4; ++i) {
            int idx = t + 256 * i;                  // 1024 float4 chunks
            int c = idx >> 4, f4 = idx & 15;
            const float4 v = *(const float4*)(x + (size_t)(b * 64 + c) * 4096 + m0 + f4 * 4);
            bf16x4v bv;
            bv[0] = (__bf16)v.x; bv[1] = (__bf16)v.y; bv[2] = (__bf16)v.z; bv[3] = (__bf16)v.w;
            *(bf16x4v*)(Vlds + c * KSTRIDE + f4 * 4) = bv;
        }
        __syncthreads();

        // ---- S = Q K^T (per wave: 16 q x 64 m), exp, P -> LDS (per-wave region)
#pragma unroll
        for (int mt = 0; mt < 4; ++mt) {
            const __bf16* kr = Klds + (mt * 16 + l16) * KSTRIDE;   // B[k=c][n=m]: 8 contiguous c
            bf16x8v bk0 = *(const bf16x8v*)(kr + quad * 8);
            bf16x8v bk1 = *(const bf16x8v*)(kr + 32 + quad * 8);
            floatx4 s = {0.f, 0.f, 0.f, 0.f};
            s = __builtin_amdgcn_mfma_f32_16x16x32_bf16(fq0, bk0, s, 0, 0, 0);
            s = __builtin_amdgcn_mfma_f32_16x16x32_bf16(fq1, bk1, s, 0, 0, 0);
#pragma unroll
            for (int r = 0; r < 4; ++r) {
                float p = __expf(s[r] * scale);     // D row = quad*4+r, col = mt*16+l16
                rs[r] += p;
                Plds[(w * 16 + quad * 4 + r) * KSTRIDE + mt * 16 + l16] = (__bf16)p;
            }
        }

        // ---- O += P V   (A = P[q][m] from per-wave LDS, no barrier needed)
        const __bf16* pr = Plds + (w * 16 + l16) * KSTRIDE;
        bf16x8v ap0 = *(const bf16x8v*)(pr + quad * 8);
        bf16x8v ap1 = *(const bf16x8v*)(pr + 32 + quad * 8);
        {
            const __bf16* vr0 = Vlds + (0 * 16 + l16) * KSTRIDE;
            const __bf16* vr1 = Vlds + (1 * 16 + l16) * KSTRIDE;
            const __bf16* vr2 = Vlds + (2 * 16 + l16) * KSTRIDE;
            const __bf16* vr3 = Vlds + (3 * 16 + l16) * KSTRIDE;
            o0 = __builtin_amdgcn_mfma_f32_16x16x32_bf16(ap0, *(const bf16x8v*)(vr0 + quad * 8), o0, 0, 0, 0);
            o0 = __builtin_amdgcn_mfma_f32_16x16x32_bf16(ap1, *(const bf16x8v*)(vr0 + 32 + quad * 8), o0, 0, 0, 0);
            o1 = __builtin_amdgcn_mfma_f32_16x16x32_bf16(ap0, *(const bf16x8v*)(vr1 + quad * 8), o1, 0, 0, 0);
            o1 = __builtin_amdgcn_mfma_f32_16x16x32_bf16(ap1, *(const bf16x8v*)(vr1 + 32 + quad * 8), o1, 0, 0, 0);
            o2 = __builtin_amdgcn_mfma_f32_16x16x32_bf16(ap0, *(const bf16x8v*)(vr2 + quad * 8), o2, 0, 0, 0);
            o2 = __builtin_amdgcn_mfma_f32_16x16x32_bf16(ap1, *(const bf16x8v*)(vr2 + 32 + quad * 8), o2, 0, 0, 0);
            o3 = __builtin_amdgcn_mfma_f32_16x16x32_bf16(ap0, *(const bf16x8v*)(vr3 + quad * 8), o3, 0, 0, 0);
            o3 = __builtin_amdgcn_mfma_f32_16x16x32_bf16(ap1, *(const bf16x8v*)(vr3 + 32 + quad * 8), o3, 0, 0, 0);
        }
    }

    // ---- row sums: butterfly over the 16 lanes sharing a quad (full broadcast)
    float inv[4];
#pragma unroll
    for (int r = 0; r < 4; ++r) {
        float v = rs[r];
        v += __shfl_xor(v, 1, 64);
        v += __shfl_xor(v, 2, 64);
        v += __shfl_xor(v, 4, 64);
        v += __shfl_xor(v, 8, 64);
        inv[r] = 1.0f / v;                 // row q = quad*4+r — matches O frag rows
    }

    __syncthreads();   // all waves done reading K/V/P before aliasing as Olds

    // ---- normalize + transpose through LDS for coalesced [B][C][N] stores
    floatx4 oo[4] = {o0, o1, o2, o3};
#pragma unroll
    for (int ct = 0; ct < 4; ++ct)
#pragma unroll
        for (int r = 0; r < 4; ++r)
            Olds[(ct * 16 + l16) * OSTRIDE + (w * 16 + quad * 4 + r)] = oo[ct][r] * inv[r];
    __syncthreads();

    const int c = t >> 2, seg = t & 3;
#pragma unroll
    for (int i = 0; i < 4; ++i) {
        *(float4*)(out + (size_t)(b * 64 + c) * 4096 + n0 + seg * 16 + i * 4) =
            *(const float4*)(&Olds[c * OSTRIDE + seg * 16 + i * 4]);
    }
}

// ---------------------------------------------------------------------------
extern "C" void kernel_launch(void* const* d_in, const int* in_sizes, int n_in,
                              void* d_out, int out_size, void* d_ws, size_t ws_size,
                              hipStream_t stream) {
    const float* x    = (const float*)d_in[0];   // [4][64][4096]
    const float* Wm   = (const float*)d_in[1];   // [64][64]
    const float* bias = (const float*)d_in[2];   // [64]
    float* out = (float*)d_out;                  // [4][64][4096]
    __bf16* qkT = (__bf16*)d_ws;                 // [4][4096][64] bf16 (2 MB)

    qk_kernel<<<BATCH * (NSP / 64), 256, 0, stream>>>(x, Wm, bias, qkT);
    attn_kernel<<<BATCH * (NSP / 64), 256, 0, stream>>>(x, qkT, out);
}

// Round 3
// 110.969 us; speedup vs baseline: 1.4208x; 1.4208x over previous
//
#include <hip/hip_runtime.h>
#include <hip/hip_bf16.h>

// Problem constants (fixed by reference): B=4, C=64, H=W=64, N=4096
#define BATCH 4
#define NSP   4096

typedef __bf16 bf16x8v __attribute__((ext_vector_type(8)));
typedef __bf16 bf16x4v __attribute__((ext_vector_type(4)));
typedef float  floatx4 __attribute__((ext_vector_type(4)));

// ---------------------------------------------------------------------------
// Kernel 1 (MFMA): qkT[b][n][o] = bf16( sum_c W[o][c]*x[b][c][n] + bias[o] )
// A = x^T[n][c] (staged LDS), B = W[o][c] rows (staged LDS). M=n, N=o, K=c.
// ---------------------------------------------------------------------------
__global__ __launch_bounds__(256) void qk_kernel(const float* __restrict__ x,
                                                 const float* __restrict__ Wm,
                                                 const float* __restrict__ bias,
                                                 __bf16* __restrict__ qkT) {
    __shared__ __align__(16) char smem1[18432];
    __bf16* xT   = (__bf16*)smem1;            // [64 n][72 c]
    __bf16* Wl   = (__bf16*)(smem1 + 9216);   // [64 o][72 c]
    float*  Olds = (float*)smem1;             // alias: [64 n][68 o] (17408 B)

    const int t  = threadIdx.x;
    const int b  = blockIdx.x >> 6;
    const int n0 = (blockIdx.x & 63) << 6;

#pragma unroll
    for (int i = 0; i < 16; ++i) {
        int idx = t + 256 * i;
        int r = idx >> 6, j = idx & 63;
        xT[j * 72 + r] = (__bf16)x[(b * 64 + r) * 4096 + n0 + j];  // xT[n][c]
        Wl[r * 72 + j] = (__bf16)Wm[idx];                          // Wl[o][c]
    }
    __syncthreads();

    const int w = t >> 6, lane = t & 63, quad = lane >> 4, l16 = lane & 15;
    const bf16x8v a0 = *(const bf16x8v*)(xT + (w * 16 + l16) * 72 + quad * 8);
    const bf16x8v a1 = *(const bf16x8v*)(xT + (w * 16 + l16) * 72 + 32 + quad * 8);

    floatx4 acc[4];
#pragma unroll
    for (int ot = 0; ot < 4; ++ot) {
        acc[ot] = floatx4{0.f, 0.f, 0.f, 0.f};
        bf16x8v b0 = *(const bf16x8v*)(Wl + (ot * 16 + l16) * 72 + quad * 8);
        bf16x8v b1 = *(const bf16x8v*)(Wl + (ot * 16 + l16) * 72 + 32 + quad * 8);
        acc[ot] = __builtin_amdgcn_mfma_f32_16x16x32_bf16(a0, b0, acc[ot], 0, 0, 0);
        acc[ot] = __builtin_amdgcn_mfma_f32_16x16x32_bf16(a1, b1, acc[ot], 0, 0, 0);
    }
    __syncthreads();   // all LDS frag reads done before aliasing as Olds

    // D: col(l16)=o within o-tile, row(quad*4+r)=n within wave's 16-n subtile
#pragma unroll
    for (int ot = 0; ot < 4; ++ot) {
        const float bo = bias[ot * 16 + l16];
#pragma unroll
        for (int r = 0; r < 4; ++r)
            Olds[(w * 16 + quad * 4 + r) * 68 + ot * 16 + l16] = acc[ot][r] + bo;
    }
    __syncthreads();

    const int n = t >> 2, seg = t & 3;
#pragma unroll
    for (int i = 0; i < 2; ++i) {
        bf16x8v pk;
#pragma unroll
        for (int k = 0; k < 8; ++k)
            pk[k] = (__bf16)Olds[n * 68 + seg * 16 + i * 8 + k];
        *(bf16x8v*)(qkT + (size_t)(b * 4096 + n0 + n) * 64 + seg * 16 + i * 8) = pk;
    }
}

// ---------------------------------------------------------------------------
// Kernel 2: flash-style attention, m-split 4-way across blocks.
// Block = (b, 64-query tile qt, m-chunk s of 1024). Writes UNNORMALIZED
// O-partials (bf16) + rowsum partials. Grid 1024 -> 4 blocks/CU, 16 waves/CU.
// ---------------------------------------------------------------------------
#define KSTRIDE 72   // bf16 elems per LDS row (144 B, 16B-aligned)
#define OSTRIDE 68   // fp32 elems per epilogue LDS row

__global__ __launch_bounds__(256, 4) void attn_kernel(const float* __restrict__ x,
                                                      const __bf16* __restrict__ qkT,
                                                      __bf16* __restrict__ Opart,
                                                      float* __restrict__ Lpart) {
    __shared__ __align__(16) char smem[27648];
    __bf16* Klds = (__bf16*)smem;                 // [64 m][KSTRIDE c]
    __bf16* Vlds = (__bf16*)(smem + 9216);        // [64 c][KSTRIDE m]
    __bf16* Plds = (__bf16*)(smem + 18432);       // [4 waves][16 q][KSTRIDE m]
    float*  Olds = (float*)smem;                  // epilogue alias: [64 c][OSTRIDE q]

    const int t   = threadIdx.x;
    // XCD swizzle: XCD ~ blk%8; pin each b to 2 XCDs for L2 locality.
    const int blk = blockIdx.x;
    const int xcd = blk & 7;
    const int b   = xcd >> 1;
    const int sub = ((blk >> 3) << 1) | (xcd & 1);   // 0..255
    const int qt  = sub >> 2;
    const int s   = sub & 3;
    const int n0  = qt << 6;
    const int pblk = (b * 64 + qt) * 4 + s;

    const int w = t >> 6, lane = t & 63, quad = lane >> 4, l16 = lane & 15;

    // Q A-frags: A[m=l16][k=quad*8+j], k = channel c
    const __bf16* qrow = qkT + (size_t)(b * 4096 + n0 + w * 16 + l16) * 64;
    const bf16x8v fq0 = *(const bf16x8v*)(qrow + quad * 8);
    const bf16x8v fq1 = *(const bf16x8v*)(qrow + 32 + quad * 8);

    floatx4 o0 = {0.f, 0.f, 0.f, 0.f};
    floatx4 o1 = {0.f, 0.f, 0.f, 0.f};
    floatx4 o2 = {0.f, 0.f, 0.f, 0.f};
    floatx4 o3 = {0.f, 0.f, 0.f, 0.f};
    float rs[4] = {0.f, 0.f, 0.f, 0.f};
    const float scale = 1.0f / 4096.0f;

    for (int it = 0; it < 16; ++it) {
        const int m0 = (s << 10) + (it << 6);
        __syncthreads();
        // stage K tile: Klds[m][c] = qkT[b][m0+m][c]
#pragma unroll
        for (int i = 0; i < 2; ++i) {
            int idx = t + 256 * i;
            int row = idx >> 3, c8 = idx & 7;
            *(uint4*)(Klds + row * KSTRIDE + c8 * 8) =
                *(const uint4*)(qkT + (size_t)(b * 4096 + m0 + row) * 64 + c8 * 8);
        }
        // stage V tile: Vlds[c][m] = bf16(x[b][c][m0+m])
#pragma unroll
        for (int i = 0; i < 4; ++i) {
            int idx = t + 256 * i;
            int c = idx >> 4, f4 = idx & 15;
            const float4 v = *(const float4*)(x + (size_t)(b * 64 + c) * 4096 + m0 + f4 * 4);
            bf16x4v bv;
            bv[0] = (__bf16)v.x; bv[1] = (__bf16)v.y; bv[2] = (__bf16)v.z; bv[3] = (__bf16)v.w;
            *(bf16x4v*)(Vlds + c * KSTRIDE + f4 * 4) = bv;
        }
        __syncthreads();

        // S = Q K^T, exp, P -> per-wave LDS region (no barrier)
#pragma unroll
        for (int mt = 0; mt < 4; ++mt) {
            const __bf16* kr = Klds + (mt * 16 + l16) * KSTRIDE;
            bf16x8v bk0 = *(const bf16x8v*)(kr + quad * 8);
            bf16x8v bk1 = *(const bf16x8v*)(kr + 32 + quad * 8);
            floatx4 sA = {0.f, 0.f, 0.f, 0.f};
            sA = __builtin_amdgcn_mfma_f32_16x16x32_bf16(fq0, bk0, sA, 0, 0, 0);
            sA = __builtin_amdgcn_mfma_f32_16x16x32_bf16(fq1, bk1, sA, 0, 0, 0);
#pragma unroll
            for (int r = 0; r < 4; ++r) {
                float p = __expf(sA[r] * scale);
                rs[r] += p;
                Plds[(w * 16 + quad * 4 + r) * KSTRIDE + mt * 16 + l16] = (__bf16)p;
            }
        }

        // O += P V
        const __bf16* pr = Plds + (w * 16 + l16) * KSTRIDE;
        bf16x8v ap0 = *(const bf16x8v*)(pr + quad * 8);
        bf16x8v ap1 = *(const bf16x8v*)(pr + 32 + quad * 8);
        {
            const __bf16* vr0 = Vlds + (0 * 16 + l16) * KSTRIDE;
            const __bf16* vr1 = Vlds + (1 * 16 + l16) * KSTRIDE;
            const __bf16* vr2 = Vlds + (2 * 16 + l16) * KSTRIDE;
            const __bf16* vr3 = Vlds + (3 * 16 + l16) * KSTRIDE;
            o0 = __builtin_amdgcn_mfma_f32_16x16x32_bf16(ap0, *(const bf16x8v*)(vr0 + quad * 8), o0, 0, 0, 0);
            o0 = __builtin_amdgcn_mfma_f32_16x16x32_bf16(ap1, *(const bf16x8v*)(vr0 + 32 + quad * 8), o0, 0, 0, 0);
            o1 = __builtin_amdgcn_mfma_f32_16x16x32_bf16(ap0, *(const bf16x8v*)(vr1 + quad * 8), o1, 0, 0, 0);
            o1 = __builtin_amdgcn_mfma_f32_16x16x32_bf16(ap1, *(const bf16x8v*)(vr1 + 32 + quad * 8), o1, 0, 0, 0);
            o2 = __builtin_amdgcn_mfma_f32_16x16x32_bf16(ap0, *(const bf16x8v*)(vr2 + quad * 8), o2, 0, 0, 0);
            o2 = __builtin_amdgcn_mfma_f32_16x16x32_bf16(ap1, *(const bf16x8v*)(vr2 + 32 + quad * 8), o2, 0, 0, 0);
            o3 = __builtin_amdgcn_mfma_f32_16x16x32_bf16(ap0, *(const bf16x8v*)(vr3 + quad * 8), o3, 0, 0, 0);
            o3 = __builtin_amdgcn_mfma_f32_16x16x32_bf16(ap1, *(const bf16x8v*)(vr3 + 32 + quad * 8), o3, 0, 0, 0);
        }
    }

    // full row sums (within this m-chunk): butterfly over the quad's 16 lanes
#pragma unroll
    for (int r = 0; r < 4; ++r) {
        float v = rs[r];
        v += __shfl_xor(v, 1, 64);
        v += __shfl_xor(v, 2, 64);
        v += __shfl_xor(v, 4, 64);
        v += __shfl_xor(v, 8, 64);
        if (l16 == 0)
            Lpart[(size_t)pblk * 64 + w * 16 + quad * 4 + r] = v;
    }

    __syncthreads();   // all K/V/P reads done before aliasing as Olds

    // transpose unnormalized O through LDS -> coalesced bf16 partial stores
    floatx4 oo[4] = {o0, o1, o2, o3};
#pragma unroll
    for (int ct = 0; ct < 4; ++ct)
#pragma unroll
        for (int r = 0; r < 4; ++r)
            Olds[(ct * 16 + l16) * OSTRIDE + (w * 16 + quad * 4 + r)] = oo[ct][r];
    __syncthreads();

    const int c = t >> 2, seg = t & 3;
    const size_t obase = (size_t)pblk * 4096 + c * 64 + seg * 16;
#pragma unroll
    for (int i = 0; i < 2; ++i) {
        bf16x8v pk;
#pragma unroll
        for (int k = 0; k < 8; ++k)
            pk[k] = (__bf16)Olds[c * OSTRIDE + seg * 16 + i * 8 + k];
        *(bf16x8v*)(Opart + obase + i * 8) = pk;
    }
}

// ---------------------------------------------------------------------------
// Kernel 3: combine the 4 m-chunk partials, normalize, store fp32 output.
// ---------------------------------------------------------------------------
__global__ __launch_bounds__(256) void reduce_kernel(const __bf16* __restrict__ Opart,
                                                     const float* __restrict__ Lpart,
                                                     float* __restrict__ out) {
    __shared__ float linv[64];
    const int blk = blockIdx.x;        // b*64 + qt
    const int b = blk >> 6, qt = blk & 63;
    const int t = threadIdx.x;

    if (t < 64) {
        float sl = 0.f;
#pragma unroll
        for (int ss = 0; ss < 4; ++ss)
            sl += Lpart[((size_t)blk * 4 + ss) * 64 + t];
        linv[t] = 1.0f / sl;
    }
    __syncthreads();

    const int c = t >> 2, seg = t & 3;
    float acc[16];
#pragma unroll
    for (int k = 0; k < 16; ++k) acc[k] = 0.f;
#pragma unroll
    for (int ss = 0; ss < 4; ++ss) {
        const __bf16* p = Opart + ((size_t)blk * 4 + ss) * 4096 + c * 64 + seg * 16;
        bf16x8v v0 = *(const bf16x8v*)p;
        bf16x8v v1 = *(const bf16x8v*)(p + 8);
#pragma unroll
        for (int k = 0; k < 8; ++k) { acc[k] += (float)v0[k]; acc[8 + k] += (float)v1[k]; }
    }
    float* op = out + (size_t)(b * 64 + c) * 4096 + qt * 64 + seg * 16;
#pragma unroll
    for (int k = 0; k < 16; ++k) acc[k] *= linv[seg * 16 + k];
#pragma unroll
    for (int i = 0; i < 4; ++i) {
        float4 vv = {acc[i * 4], acc[i * 4 + 1], acc[i * 4 + 2], acc[i * 4 + 3]};
        *(float4*)(op + i * 4) = vv;
    }
}

// ---------------------------------------------------------------------------
extern "C" void kernel_launch(void* const* d_in, const int* in_sizes, int n_in,
                              void* d_out, int out_size, void* d_ws, size_t ws_size,
                              hipStream_t stream) {
    const float* x    = (const float*)d_in[0];   // [4][64][4096]
    const float* Wm   = (const float*)d_in[1];   // [64][64]
    const float* bias = (const float*)d_in[2];   // [64]
    float* out = (float*)d_out;                  // [4][64][4096]

    char* ws = (char*)d_ws;
    __bf16* qkT   = (__bf16*)ws;                            // 2 MB  [4][4096][64]
    __bf16* Opart = (__bf16*)(ws + 2097152);                // 8 MB  [1024][64 c][64 q]
    float*  Lpart = (float*)(ws + 2097152 + 8388608);       // 256 KB [1024][64 q]

    qk_kernel<<<BATCH * (NSP / 64), 256, 0, stream>>>(x, Wm, bias, qkT);
    attn_kernel<<<BATCH * 64 * 4, 256, 0, stream>>>(x, qkT, Opart, Lpart);
    reduce_kernel<<<BATCH * 64, 256, 0, stream>>>(Opart, Lpart, out);
}

// Round 4
// 101.774 us; speedup vs baseline: 1.5491x; 1.0903x over previous
//
#include <hip/hip_runtime.h>
#include <hip/hip_bf16.h>

// Problem constants (fixed by reference): B=4, C=64, H=W=64, N=4096
#define BATCH 4
#define NSP   4096

typedef __bf16 bf16x8v __attribute__((ext_vector_type(8)));
typedef __bf16 bf16x4v __attribute__((ext_vector_type(4)));
typedef float  floatx4 __attribute__((ext_vector_type(4)));

// ---------------------------------------------------------------------------
// Kernel 1: qkT[b][n][o] = bf16( (sum_c W[o][c]*x[b][c][n] + bias[o]) / 64 )
// The 1/64 pre-scale makes attn scores come out already scaled by 1/4096
// (both Q and K carry 1/64). One wave per block, 1024 blocks (4 waves/CU).
// ---------------------------------------------------------------------------
__global__ __launch_bounds__(64) void qk_kernel(const float* __restrict__ x,
                                                const float* __restrict__ Wm,
                                                const float* __restrict__ bias,
                                                __bf16* __restrict__ qkT) {
    __shared__ __align__(16) __bf16 xT[16 * 72];   // xT[n][c] (also reused as out buf)

    const int t  = threadIdx.x;
    const int b  = blockIdx.x >> 8;
    const int n0 = (blockIdx.x & 255) << 4;

    // stage x^T tile, pre-scaled by 1/64
#pragma unroll
    for (int i = 0; i < 16; ++i) {
        int idx = t + 64 * i;
        int c = idx >> 4, n = idx & 15;
        xT[n * 72 + c] = (__bf16)(x[(size_t)(b * 64 + c) * 4096 + n0 + n] * 0.015625f);
    }
    __syncthreads();

    const int quad = t >> 4, l16 = t & 15;
    // A-frags: A[n=l16][c=quad*8+j]
    const bf16x8v a0 = *(const bf16x8v*)(xT + l16 * 72 + quad * 8);
    const bf16x8v a1 = *(const bf16x8v*)(xT + l16 * 72 + 32 + quad * 8);

    floatx4 acc[4];
#pragma unroll
    for (int ot = 0; ot < 4; ++ot) {
        // B-frags straight from global W (fp32 -> bf16): B[k=c][n=o], o=ot*16+l16
        const float* wr = Wm + (ot * 16 + l16) * 64;
        float4 wa = *(const float4*)(wr + quad * 8);
        float4 wb = *(const float4*)(wr + quad * 8 + 4);
        float4 wc = *(const float4*)(wr + 32 + quad * 8);
        float4 wd = *(const float4*)(wr + 32 + quad * 8 + 4);
        bf16x8v b0, b1;
        b0[0]=(__bf16)wa.x; b0[1]=(__bf16)wa.y; b0[2]=(__bf16)wa.z; b0[3]=(__bf16)wa.w;
        b0[4]=(__bf16)wb.x; b0[5]=(__bf16)wb.y; b0[6]=(__bf16)wb.z; b0[7]=(__bf16)wb.w;
        b1[0]=(__bf16)wc.x; b1[1]=(__bf16)wc.y; b1[2]=(__bf16)wc.z; b1[3]=(__bf16)wc.w;
        b1[4]=(__bf16)wd.x; b1[5]=(__bf16)wd.y; b1[6]=(__bf16)wd.z; b1[7]=(__bf16)wd.w;
        acc[ot] = floatx4{0.f, 0.f, 0.f, 0.f};
        acc[ot] = __builtin_amdgcn_mfma_f32_16x16x32_bf16(a0, b0, acc[ot], 0, 0, 0);
        acc[ot] = __builtin_amdgcn_mfma_f32_16x16x32_bf16(a1, b1, acc[ot], 0, 0, 0);
    }
    __syncthreads();   // xT frag reads done before reuse

    // D: row(quad*4+r)=n_local, col(l16)=o_local. Stash bf16 into LDS [n][o].
#pragma unroll
    for (int ot = 0; ot < 4; ++ot) {
        const float bo = bias[ot * 16 + l16] * 0.015625f;
#pragma unroll
        for (int r = 0; r < 4; ++r)
            xT[(quad * 4 + r) * 72 + ot * 16 + l16] = (__bf16)(acc[ot][r] + bo);
    }
    __syncthreads();

    const int n = t >> 2, seg = t & 3;
    __bf16* dst = qkT + (size_t)(b * 4096 + n0 + n) * 64 + seg * 16;
    *(bf16x8v*)dst       = *(const bf16x8v*)(xT + n * 72 + seg * 16);
    *(bf16x8v*)(dst + 8) = *(const bf16x8v*)(xT + n * 72 + seg * 16 + 8);
}

// ---------------------------------------------------------------------------
// Kernel 2: flash-style attention. Block = (b, 128-q tile, m-chunk). 4 waves,
// each wave owns 32 q. S^T = K·Q^T (operand swap) so exp results are
// m-contiguous per lane -> packed b64 P writes. Unnormalized bf16 O-partials
// + rowsum partials out; reduce_kernel combines.
// ---------------------------------------------------------------------------
template<int SPLIT, int ITERS>
__global__ __launch_bounds__(256, 4) void attn_kernel(const float* __restrict__ x,
                                                      const __bf16* __restrict__ qkT,
                                                      __bf16* __restrict__ Opart,
                                                      float* __restrict__ Lpart) {
    __shared__ __align__(16) char smem[36864];
    __bf16* Klds = (__bf16*)smem;                 // [64 m][72 c]
    __bf16* Vlds = (__bf16*)(smem + 9216);        // [64 c][72 m]
    __bf16* Plds = (__bf16*)(smem + 18432);       // [128 q][72 m] (per-wave 32-q slabs)
    float*  Olds = (float*)smem;                  // epilogue alias: [64 c][132 q]

    const int t   = threadIdx.x;
    const int blk = blockIdx.x;
    const int xcd = blk & 7;                      // XCD round-robin
    const int b   = xcd >> 1;                     // each b pinned to 2 XCDs
    const int sub = ((blk >> 3) << 1) | (xcd & 1);
    const int qt  = sub / SPLIT;                  // 0..31 (128-q tiles)
    const int s   = sub % SPLIT;
    const int n0  = qt << 7;
    const int pblk = (b * 32 + qt) * SPLIT + s;

    const int w = t >> 6, lane = t & 63, quad = lane >> 4, l16 = lane & 15;

    // Q B-frags: B[k=c][n=q], q = w*32 + qt2*16 + l16
    bf16x8v fq[2][2];
#pragma unroll
    for (int qt2 = 0; qt2 < 2; ++qt2) {
        const __bf16* qrow = qkT + (size_t)(b * 4096 + n0 + w * 32 + qt2 * 16 + l16) * 64;
        fq[qt2][0] = *(const bf16x8v*)(qrow + quad * 8);
        fq[qt2][1] = *(const bf16x8v*)(qrow + 32 + quad * 8);
    }

    floatx4 oacc[2][4];
#pragma unroll
    for (int i = 0; i < 2; ++i)
#pragma unroll
        for (int j = 0; j < 4; ++j) oacc[i][j] = floatx4{0.f, 0.f, 0.f, 0.f};
    float rs[2] = {0.f, 0.f};

    for (int it = 0; it < ITERS; ++it) {
        const int m0 = s * (64 * ITERS) + (it << 6);
        __syncthreads();
        // stage K tile: Klds[m][c] (16B chunks)
#pragma unroll
        for (int i = 0; i < 2; ++i) {
            int idx = t + 256 * i;
            int row = idx >> 3, c8 = idx & 7;
            *(uint4*)(Klds + row * 72 + c8 * 8) =
                *(const uint4*)(qkT + (size_t)(b * 4096 + m0 + row) * 64 + c8 * 8);
        }
        // stage V tile: Vlds[c][m] = bf16(x[b][c][m0+m])
#pragma unroll
        for (int i = 0; i < 4; ++i) {
            int idx = t + 256 * i;
            int c = idx >> 4, f4 = idx & 15;
            const float4 v = *(const float4*)(x + (size_t)(b * 64 + c) * 4096 + m0 + f4 * 4);
            bf16x4v bv;
            bv[0] = (__bf16)v.x; bv[1] = (__bf16)v.y; bv[2] = (__bf16)v.z; bv[3] = (__bf16)v.w;
            *(bf16x4v*)(Vlds + c * 72 + f4 * 4) = bv;
        }
        __syncthreads();

        // S^T = K·Q^T: D row = m_local = quad*4+r (contiguous in r!), col = q = l16
#pragma unroll
        for (int mt = 0; mt < 4; ++mt) {
            const __bf16* kr = Klds + (mt * 16 + l16) * 72;     // A[m=l16][c=quad*8+j]
            bf16x8v ak0 = *(const bf16x8v*)(kr + quad * 8);
            bf16x8v ak1 = *(const bf16x8v*)(kr + 32 + quad * 8);
#pragma unroll
            for (int qt2 = 0; qt2 < 2; ++qt2) {
                floatx4 sT = {0.f, 0.f, 0.f, 0.f};
                sT = __builtin_amdgcn_mfma_f32_16x16x32_bf16(ak0, fq[qt2][0], sT, 0, 0, 0);
                sT = __builtin_amdgcn_mfma_f32_16x16x32_bf16(ak1, fq[qt2][1], sT, 0, 0, 0);
                float p0 = __expf(sT[0]), p1 = __expf(sT[1]);
                float p2 = __expf(sT[2]), p3 = __expf(sT[3]);
                rs[qt2] += (p0 + p1) + (p2 + p3);
                bf16x4v pv;
                pv[0] = (__bf16)p0; pv[1] = (__bf16)p1; pv[2] = (__bf16)p2; pv[3] = (__bf16)p3;
                *(bf16x4v*)(Plds + (w * 32 + qt2 * 16 + l16) * 72 + mt * 16 + quad * 4) = pv;
            }
        }

        // O += P·V  (A = P[q][m] rows from per-wave LDS slab — no barrier)
        bf16x8v ap[2][2];
#pragma unroll
        for (int qt2 = 0; qt2 < 2; ++qt2) {
            const __bf16* pr = Plds + (w * 32 + qt2 * 16 + l16) * 72;
            ap[qt2][0] = *(const bf16x8v*)(pr + quad * 8);
            ap[qt2][1] = *(const bf16x8v*)(pr + 32 + quad * 8);
        }
#pragma unroll
        for (int ct = 0; ct < 4; ++ct) {
            const __bf16* vr = Vlds + (ct * 16 + l16) * 72;     // B[k=m][n=c]
            bf16x8v bv0 = *(const bf16x8v*)(vr + quad * 8);
            bf16x8v bv1 = *(const bf16x8v*)(vr + 32 + quad * 8);
#pragma unroll
            for (int qt2 = 0; qt2 < 2; ++qt2) {
                oacc[qt2][ct] = __builtin_amdgcn_mfma_f32_16x16x32_bf16(ap[qt2][0], bv0, oacc[qt2][ct], 0, 0, 0);
                oacc[qt2][ct] = __builtin_amdgcn_mfma_f32_16x16x32_bf16(ap[qt2][1], bv1, oacc[qt2][ct], 0, 0, 0);
            }
        }
    }

    // rowsum: lane holds partial for q=qt2*16+l16 over its quad's m-rows;
    // reduce across quads = lanes differing in bits 4..5.
#pragma unroll
    for (int qt2 = 0; qt2 < 2; ++qt2) {
        float v = rs[qt2];
        v += __shfl_xor(v, 16, 64);
        v += __shfl_xor(v, 32, 64);
        if (quad == 0)
            Lpart[(size_t)pblk * 128 + w * 32 + qt2 * 16 + l16] = v;
    }

    __syncthreads();   // all K/V/P reads done before aliasing as Olds

    // O D-layout: q = w*32 + qt2*16 + quad*4 + r, c = ct*16 + l16. Transpose to [c][q].
#pragma unroll
    for (int qt2 = 0; qt2 < 2; ++qt2)
#pragma unroll
        for (int ct = 0; ct < 4; ++ct)
#pragma unroll
            for (int r = 0; r < 4; ++r)
                Olds[(ct * 16 + l16) * 132 + w * 32 + qt2 * 16 + quad * 4 + r] = oacc[qt2][ct][r];
    __syncthreads();

    // coalesced bf16 partial stores: Opart[pblk][c][q]
    const int c = t >> 2, seg = t & 3;
#pragma unroll
    for (int i = 0; i < 4; ++i) {
        floatx4 v0 = *(const floatx4*)(Olds + c * 132 + seg * 32 + i * 8);
        floatx4 v1 = *(const floatx4*)(Olds + c * 132 + seg * 32 + i * 8 + 4);
        bf16x8v pk;
        pk[0]=(__bf16)v0[0]; pk[1]=(__bf16)v0[1]; pk[2]=(__bf16)v0[2]; pk[3]=(__bf16)v0[3];
        pk[4]=(__bf16)v1[0]; pk[5]=(__bf16)v1[1]; pk[6]=(__bf16)v1[2]; pk[7]=(__bf16)v1[3];
        *(bf16x8v*)(Opart + (size_t)pblk * 8192 + c * 128 + seg * 32 + i * 8) = pk;
    }
}

// ---------------------------------------------------------------------------
// Kernel 3: combine SPLIT m-chunk partials, normalize, store fp32 output.
// Grid 1024 (c-split 8) -> 4 blocks/CU.
// ---------------------------------------------------------------------------
template<int SPLIT>
__global__ __launch_bounds__(256) void reduce_kernel(const __bf16* __restrict__ Opart,
                                                     const float* __restrict__ Lpart,
                                                     float* __restrict__ out) {
    const int blk = blockIdx.x;           // (b*32+qt)*8 + cq
    const int bq = blk >> 3, cq = blk & 7;
    const int b = bq >> 5, qt = bq & 31;
    const int t = threadIdx.x;
    const int cl = t >> 5;                 // 0..7
    const int q4 = (t & 31) << 2;          // 0..124

    float l0 = 0.f, l1 = 0.f, l2 = 0.f, l3 = 0.f;
#pragma unroll
    for (int s = 0; s < SPLIT; ++s) {
        const float4 lv = *(const float4*)(Lpart + ((size_t)bq * SPLIT + s) * 128 + q4);
        l0 += lv.x; l1 += lv.y; l2 += lv.z; l3 += lv.w;
    }
    float a0 = 0.f, a1 = 0.f, a2 = 0.f, a3 = 0.f;
#pragma unroll
    for (int s = 0; s < SPLIT; ++s) {
        const __bf16* p = Opart + ((size_t)bq * SPLIT + s) * 8192 + (cq * 8 + cl) * 128 + q4;
        bf16x4v v = *(const bf16x4v*)p;
        a0 += (float)v[0]; a1 += (float)v[1]; a2 += (float)v[2]; a3 += (float)v[3];
    }
    float4 o;
    o.x = a0 / l0; o.y = a1 / l1; o.z = a2 / l2; o.w = a3 / l3;
    *(float4*)(out + (size_t)(b * 64 + cq * 8 + cl) * 4096 + qt * 128 + q4) = o;
}

// ---------------------------------------------------------------------------
extern "C" void kernel_launch(void* const* d_in, const int* in_sizes, int n_in,
                              void* d_out, int out_size, void* d_ws, size_t ws_size,
                              hipStream_t stream) {
    const float* x    = (const float*)d_in[0];   // [4][64][4096]
    const float* Wm   = (const float*)d_in[1];   // [64][64]
    const float* bias = (const float*)d_in[2];   // [64]
    float* out = (float*)d_out;                  // [4][64][4096]

    char* ws = (char*)d_ws;
    __bf16* qkT = (__bf16*)ws;                   // 2 MB [4][4096][64] bf16

    qk_kernel<<<BATCH * (NSP / 16), 64, 0, stream>>>(x, Wm, bias, qkT);

    const size_t QKT = 2097152;
    const size_t needBig = QKT + (size_t)1024 * 8192 * 2 + (size_t)1024 * 128 * 4;  // ~19.4 MB
    if (ws_size >= needBig) {
        __bf16* Opart = (__bf16*)(ws + QKT);                          // 16 MB [1024][64][128]
        float*  Lpart = (float*)(ws + QKT + (size_t)1024 * 8192 * 2); // 512 KB
        attn_kernel<8, 8><<<BATCH * 32 * 8, 256, 0, stream>>>(x, qkT, Opart, Lpart);
        reduce_kernel<8><<<1024, 256, 0, stream>>>(Opart, Lpart, out);
    } else {
        __bf16* Opart = (__bf16*)(ws + QKT);                          // 8 MB [512][64][128]
        float*  Lpart = (float*)(ws + QKT + (size_t)512 * 8192 * 2);  // 256 KB
        attn_kernel<4, 16><<<BATCH * 32 * 4, 256, 0, stream>>>(x, qkT, Opart, Lpart);
        reduce_kernel<4><<<1024, 256, 0, stream>>>(Opart, Lpart, out);
    }
}

// Round 5
// 101.198 us; speedup vs baseline: 1.5579x; 1.0057x over previous
//
#include <hip/hip_runtime.h>
#include <hip/hip_bf16.h>

// Problem constants (fixed by reference): B=4, C=64, H=W=64, N=4096
#define BATCH 4
#define NSP   4096

typedef __bf16 bf16x8v __attribute__((ext_vector_type(8)));
typedef __bf16 bf16x4v __attribute__((ext_vector_type(4)));
typedef float  floatx4 __attribute__((ext_vector_type(4)));

// ---------------------------------------------------------------------------
// Kernel 1: qkT[b][n][o] = bf16( (sum_c W[o][c]*x[b][c][n] + bias[o]) / 64 )
// 1/64 pre-scale on both Q and K makes attn scores come out scaled by 1/4096.
// 256 blocks x 256 thr; block = 64-n tile; float4 staging, MFMA, b128 stores.
// ---------------------------------------------------------------------------
__global__ __launch_bounds__(256) void qk_kernel(const float* __restrict__ x,
                                                 const float* __restrict__ Wm,
                                                 const float* __restrict__ bias,
                                                 __bf16* __restrict__ qkT) {
    __shared__ __align__(16) __bf16 xT[64 * 72];   // [n][c]; reused as [n][o] out buf

    const int t  = threadIdx.x;
    const int b  = blockIdx.x >> 6;
    const int n0 = (blockIdx.x & 63) << 6;

    // stage x^T tile, pre-scaled by 1/64, coalesced float4 reads
#pragma unroll
    for (int p = 0; p < 4; ++p) {
        const int c  = p * 16 + (t >> 4);
        const int n4 = (t & 15) * 4;
        const float4 v = *(const float4*)(x + (size_t)(b * 64 + c) * 4096 + n0 + n4);
        xT[(n4 + 0) * 72 + c] = (__bf16)(v.x * 0.015625f);
        xT[(n4 + 1) * 72 + c] = (__bf16)(v.y * 0.015625f);
        xT[(n4 + 2) * 72 + c] = (__bf16)(v.z * 0.015625f);
        xT[(n4 + 3) * 72 + c] = (__bf16)(v.w * 0.015625f);
    }
    __syncthreads();

    const int w = t >> 6, lane = t & 63, quad = lane >> 4, l16 = lane & 15;
    // A-frags: A[n=l16][c=quad*8+j], wave w owns n-rows w*16..+15
    const bf16x8v a0 = *(const bf16x8v*)(xT + (w * 16 + l16) * 72 + quad * 8);
    const bf16x8v a1 = *(const bf16x8v*)(xT + (w * 16 + l16) * 72 + 32 + quad * 8);

    floatx4 acc[4];
#pragma unroll
    for (int ot = 0; ot < 4; ++ot) {
        // B-frags straight from global W (fp32 -> bf16): B[k=c][n=o], o=ot*16+l16
        const float* wr = Wm + (ot * 16 + l16) * 64;
        float4 wa = *(const float4*)(wr + quad * 8);
        float4 wb = *(const float4*)(wr + quad * 8 + 4);
        float4 wc = *(const float4*)(wr + 32 + quad * 8);
        float4 wd = *(const float4*)(wr + 32 + quad * 8 + 4);
        bf16x8v b0, b1;
        b0[0]=(__bf16)wa.x; b0[1]=(__bf16)wa.y; b0[2]=(__bf16)wa.z; b0[3]=(__bf16)wa.w;
        b0[4]=(__bf16)wb.x; b0[5]=(__bf16)wb.y; b0[6]=(__bf16)wb.z; b0[7]=(__bf16)wb.w;
        b1[0]=(__bf16)wc.x; b1[1]=(__bf16)wc.y; b1[2]=(__bf16)wc.z; b1[3]=(__bf16)wc.w;
        b1[4]=(__bf16)wd.x; b1[5]=(__bf16)wd.y; b1[6]=(__bf16)wd.z; b1[7]=(__bf16)wd.w;
        acc[ot] = floatx4{0.f, 0.f, 0.f, 0.f};
        acc[ot] = __builtin_amdgcn_mfma_f32_16x16x32_bf16(a0, b0, acc[ot], 0, 0, 0);
        acc[ot] = __builtin_amdgcn_mfma_f32_16x16x32_bf16(a1, b1, acc[ot], 0, 0, 0);
    }
    __syncthreads();   // all xT frag reads done before reuse as [n][o]

    // D: row(quad*4+r)=n_local within wave's 16-n, col(l16)=o_local
#pragma unroll
    for (int ot = 0; ot < 4; ++ot) {
        const float bo = bias[ot * 16 + l16] * 0.015625f;
#pragma unroll
        for (int r = 0; r < 4; ++r)
            xT[(w * 16 + quad * 4 + r) * 72 + ot * 16 + l16] = (__bf16)(acc[ot][r] + bo);
    }
    __syncthreads();

    const int n = t >> 2, seg = t & 3;
    __bf16* dst = qkT + (size_t)(b * 4096 + n0 + n) * 64 + seg * 16;
    *(bf16x8v*)dst       = *(const bf16x8v*)(xT + n * 72 + seg * 16);
    *(bf16x8v*)(dst + 8) = *(const bf16x8v*)(xT + n * 72 + seg * 16 + 8);
}

// ---------------------------------------------------------------------------
// Kernel 2: flash-style attention (UNCHANGED from R4). Block = (b, 128-q tile,
// m-chunk). 4 waves x 32 q. S^T = K·Q^T so exp results are m-contiguous ->
// packed b64 P writes. Unnormalized bf16 O-partials + rowsums out.
// ---------------------------------------------------------------------------
template<int SPLIT, int ITERS>
__global__ __launch_bounds__(256, 4) void attn_kernel(const float* __restrict__ x,
                                                      const __bf16* __restrict__ qkT,
                                                      __bf16* __restrict__ Opart,
                                                      float* __restrict__ Lpart) {
    __shared__ __align__(16) char smem[36864];
    __bf16* Klds = (__bf16*)smem;                 // [64 m][72 c]
    __bf16* Vlds = (__bf16*)(smem + 9216);        // [64 c][72 m]
    __bf16* Plds = (__bf16*)(smem + 18432);       // [128 q][72 m] (per-wave 32-q slabs)
    float*  Olds = (float*)smem;                  // epilogue alias: [64 c][132 q]

    const int t   = threadIdx.x;
    const int blk = blockIdx.x;
    const int xcd = blk & 7;                      // XCD round-robin
    const int b   = xcd >> 1;                     // each b pinned to 2 XCDs
    const int sub = ((blk >> 3) << 1) | (xcd & 1);
    const int qt  = sub / SPLIT;
    const int s   = sub % SPLIT;
    const int n0  = qt << 7;
    const int pblk = (b * 32 + qt) * SPLIT + s;

    const int w = t >> 6, lane = t & 63, quad = lane >> 4, l16 = lane & 15;

    // Q B-frags: B[k=c][n=q], q = w*32 + qt2*16 + l16
    bf16x8v fq[2][2];
#pragma unroll
    for (int qt2 = 0; qt2 < 2; ++qt2) {
        const __bf16* qrow = qkT + (size_t)(b * 4096 + n0 + w * 32 + qt2 * 16 + l16) * 64;
        fq[qt2][0] = *(const bf16x8v*)(qrow + quad * 8);
        fq[qt2][1] = *(const bf16x8v*)(qrow + 32 + quad * 8);
    }

    floatx4 oacc[2][4];
#pragma unroll
    for (int i = 0; i < 2; ++i)
#pragma unroll
        for (int j = 0; j < 4; ++j) oacc[i][j] = floatx4{0.f, 0.f, 0.f, 0.f};
    float rs[2] = {0.f, 0.f};

    for (int it = 0; it < ITERS; ++it) {
        const int m0 = s * (64 * ITERS) + (it << 6);
        __syncthreads();
#pragma unroll
        for (int i = 0; i < 2; ++i) {
            int idx = t + 256 * i;
            int row = idx >> 3, c8 = idx & 7;
            *(uint4*)(Klds + row * 72 + c8 * 8) =
                *(const uint4*)(qkT + (size_t)(b * 4096 + m0 + row) * 64 + c8 * 8);
        }
#pragma unroll
        for (int i = 0; i < 4; ++i) {
            int idx = t + 256 * i;
            int c = idx >> 4, f4 = idx & 15;
            const float4 v = *(const float4*)(x + (size_t)(b * 64 + c) * 4096 + m0 + f4 * 4);
            bf16x4v bv;
            bv[0] = (__bf16)v.x; bv[1] = (__bf16)v.y; bv[2] = (__bf16)v.z; bv[3] = (__bf16)v.w;
            *(bf16x4v*)(Vlds + c * 72 + f4 * 4) = bv;
        }
        __syncthreads();

        // S^T = K·Q^T: D row = m_local = quad*4+r, col = q = l16
#pragma unroll
        for (int mt = 0; mt < 4; ++mt) {
            const __bf16* kr = Klds + (mt * 16 + l16) * 72;
            bf16x8v ak0 = *(const bf16x8v*)(kr + quad * 8);
            bf16x8v ak1 = *(const bf16x8v*)(kr + 32 + quad * 8);
#pragma unroll
            for (int qt2 = 0; qt2 < 2; ++qt2) {
                floatx4 sT = {0.f, 0.f, 0.f, 0.f};
                sT = __builtin_amdgcn_mfma_f32_16x16x32_bf16(ak0, fq[qt2][0], sT, 0, 0, 0);
                sT = __builtin_amdgcn_mfma_f32_16x16x32_bf16(ak1, fq[qt2][1], sT, 0, 0, 0);
                float p0 = __expf(sT[0]), p1 = __expf(sT[1]);
                float p2 = __expf(sT[2]), p3 = __expf(sT[3]);
                rs[qt2] += (p0 + p1) + (p2 + p3);
                bf16x4v pv;
                pv[0] = (__bf16)p0; pv[1] = (__bf16)p1; pv[2] = (__bf16)p2; pv[3] = (__bf16)p3;
                *(bf16x4v*)(Plds + (w * 32 + qt2 * 16 + l16) * 72 + mt * 16 + quad * 4) = pv;
            }
        }

        // O += P·V
        bf16x8v ap[2][2];
#pragma unroll
        for (int qt2 = 0; qt2 < 2; ++qt2) {
            const __bf16* pr = Plds + (w * 32 + qt2 * 16 + l16) * 72;
            ap[qt2][0] = *(const bf16x8v*)(pr + quad * 8);
            ap[qt2][1] = *(const bf16x8v*)(pr + 32 + quad * 8);
        }
#pragma unroll
        for (int ct = 0; ct < 4; ++ct) {
            const __bf16* vr = Vlds + (ct * 16 + l16) * 72;
            bf16x8v bv0 = *(const bf16x8v*)(vr + quad * 8);
            bf16x8v bv1 = *(const bf16x8v*)(vr + 32 + quad * 8);
#pragma unroll
            for (int qt2 = 0; qt2 < 2; ++qt2) {
                oacc[qt2][ct] = __builtin_amdgcn_mfma_f32_16x16x32_bf16(ap[qt2][0], bv0, oacc[qt2][ct], 0, 0, 0);
                oacc[qt2][ct] = __builtin_amdgcn_mfma_f32_16x16x32_bf16(ap[qt2][1], bv1, oacc[qt2][ct], 0, 0, 0);
            }
        }
    }

#pragma unroll
    for (int qt2 = 0; qt2 < 2; ++qt2) {
        float v = rs[qt2];
        v += __shfl_xor(v, 16, 64);
        v += __shfl_xor(v, 32, 64);
        if (quad == 0)
            Lpart[(size_t)pblk * 128 + w * 32 + qt2 * 16 + l16] = v;
    }

    __syncthreads();

#pragma unroll
    for (int qt2 = 0; qt2 < 2; ++qt2)
#pragma unroll
        for (int ct = 0; ct < 4; ++ct)
#pragma unroll
            for (int r = 0; r < 4; ++r)
                Olds[(ct * 16 + l16) * 132 + w * 32 + qt2 * 16 + quad * 4 + r] = oacc[qt2][ct][r];
    __syncthreads();

    const int c = t >> 2, seg = t & 3;
#pragma unroll
    for (int i = 0; i < 4; ++i) {
        floatx4 v0 = *(const floatx4*)(Olds + c * 132 + seg * 32 + i * 8);
        floatx4 v1 = *(const floatx4*)(Olds + c * 132 + seg * 32 + i * 8 + 4);
        bf16x8v pk;
        pk[0]=(__bf16)v0[0]; pk[1]=(__bf16)v0[1]; pk[2]=(__bf16)v0[2]; pk[3]=(__bf16)v0[3];
        pk[4]=(__bf16)v1[0]; pk[5]=(__bf16)v1[1]; pk[6]=(__bf16)v1[2]; pk[7]=(__bf16)v1[3];
        *(bf16x8v*)(Opart + (size_t)pblk * 8192 + c * 128 + seg * 32 + i * 8) = pk;
    }
}

// ---------------------------------------------------------------------------
// Kernel 3: combine SPLIT m-chunk partials, normalize, store fp32 output.
// 512 blocks x 256 thr; 16B Opart loads, 8-deep MLP.
// ---------------------------------------------------------------------------
template<int SPLIT>
__global__ __launch_bounds__(256) void reduce_kernel(const __bf16* __restrict__ Opart,
                                                     const float* __restrict__ Lpart,
                                                     float* __restrict__ out) {
    const int blk = blockIdx.x;           // (b*32+qt)*4 + cq
    const int bq = blk >> 2, cq = blk & 3;
    const int b = bq >> 5, qt = bq & 31;
    const int t = threadIdx.x;
    const int c  = cq * 16 + (t >> 4);     // channel
    const int q8 = (t & 15) * 8;           // q offset (8 per thread)

    float l[8] = {0.f,0.f,0.f,0.f,0.f,0.f,0.f,0.f};
#pragma unroll
    for (int s = 0; s < SPLIT; ++s) {
        const float* lp = Lpart + ((size_t)bq * SPLIT + s) * 128 + q8;
        float4 u = *(const float4*)lp;
        float4 v = *(const float4*)(lp + 4);
        l[0]+=u.x; l[1]+=u.y; l[2]+=u.z; l[3]+=u.w;
        l[4]+=v.x; l[5]+=v.y; l[6]+=v.z; l[7]+=v.w;
    }
    float a[8] = {0.f,0.f,0.f,0.f,0.f,0.f,0.f,0.f};
#pragma unroll
    for (int s = 0; s < SPLIT; ++s) {
        bf16x8v v = *(const bf16x8v*)(Opart + ((size_t)bq * SPLIT + s) * 8192 + c * 128 + q8);
#pragma unroll
        for (int k = 0; k < 8; ++k) a[k] += (float)v[k];
    }
    float* op = out + (size_t)(b * 64 + c) * 4096 + qt * 128 + q8;
    float4 o0, o1;
    o0.x = a[0]/l[0]; o0.y = a[1]/l[1]; o0.z = a[2]/l[2]; o0.w = a[3]/l[3];
    o1.x = a[4]/l[4]; o1.y = a[5]/l[5]; o1.z = a[6]/l[6]; o1.w = a[7]/l[7];
    *(float4*)op       = o0;
    *(float4*)(op + 4) = o1;
}

// ---------------------------------------------------------------------------
extern "C" void kernel_launch(void* const* d_in, const int* in_sizes, int n_in,
                              void* d_out, int out_size, void* d_ws, size_t ws_size,
                              hipStream_t stream) {
    const float* x    = (const float*)d_in[0];   // [4][64][4096]
    const float* Wm   = (const float*)d_in[1];   // [64][64]
    const float* bias = (const float*)d_in[2];   // [64]
    float* out = (float*)d_out;                  // [4][64][4096]

    char* ws = (char*)d_ws;
    __bf16* qkT = (__bf16*)ws;                   // 2 MB [4][4096][64] bf16

    qk_kernel<<<BATCH * (NSP / 64), 256, 0, stream>>>(x, Wm, bias, qkT);

    const size_t QKT = 2097152;
    const size_t needBig = QKT + (size_t)1024 * 8192 * 2 + (size_t)1024 * 128 * 4;  // ~19.4 MB
    if (ws_size >= needBig) {
        __bf16* Opart = (__bf16*)(ws + QKT);                          // 16 MB [1024][64][128]
        float*  Lpart = (float*)(ws + QKT + (size_t)1024 * 8192 * 2); // 512 KB
        attn_kernel<8, 8><<<BATCH * 32 * 8, 256, 0, stream>>>(x, qkT, Opart, Lpart);
        reduce_kernel<8><<<512, 256, 0, stream>>>(Opart, Lpart, out);
    } else {
        __bf16* Opart = (__bf16*)(ws + QKT);                          // 8 MB [512][64][128]
        float*  Lpart = (float*)(ws + QKT + (size_t)512 * 8192 * 2);  // 256 KB
        attn_kernel<4, 16><<<BATCH * 32 * 4, 256, 0, stream>>>(x, qkT, Opart, Lpart);
        reduce_kernel<4><<<512, 256, 0, stream>>>(Opart, Lpart, out);
    }
}